// Round 9
// baseline (342.812 us; speedup 1.0000x reference)
//
#include <hip/hip_runtime.h>
#include <math.h>

#define B 8
#define N 4096
#define C 128
#define K 20
#define M (B*N)
#define CCAP 160   // candidate buffer per wave
#define CWIN 128   // acceptance window upper bound (margin 32 below CCAP)

__device__ __forceinline__ float lrelu(float x) { return x > 0.f ? x : 0.01f * x; }

__device__ __forceinline__ float pdist(float xix, float xiy, float xiz,
                                       float xjx, float xjy, float xjz) {
    float dx = xix - xjx, dy = xiy - xjy, dz = xiz - xjz;
    return fmaf(dx, dx, fmaf(dy, dy, dz * dz));   // >= 0 always
}

// ---------------- prep: weights only ----------------
__global__ void prep_all(const float* __restrict__ W1, const float* __restrict__ b1,
                         const float* __restrict__ W2, const float* __restrict__ b2,
                         float* __restrict__ wt, float* __restrict__ bias) {
    int t = blockIdx.x * 256 + threadIdx.x;       // 0..16383
    int c = t >> 7, o = t & 127;
    int oc = o * C + c;
    wt[t]             = W1[oc] * (1.f / 21.f);
    wt[C * C + t]     = W2[oc] * (1.f / 21.f);
    wt[2 * C * C + t] = (W1[C * C + oc] + W2[C * C + oc]) * 0.5f;
    wt[3 * C * C + t] = (W1[2 * C * C + oc] + W2[2 * C * C + oc]) * 0.5f;
    if (t < C) {
        bias[t]         = (b1[t] + 20.f * b2[t]) * (1.f / 21.f);
        bias[C + t]     = (b1[C + t] + b2[C + t]) * 0.5f;
        bias[2 * C + t] = (b1[2 * C + t] + b2[2 * C + t]) * 0.5f;
    }
}

// ---------------- per-batch transpose [C][N] -> [N][C] ----------------
__global__ __launch_bounds__(256) void transpose_rs(const float* __restrict__ in,
                                                    float* __restrict__ out, int R, int S) {
    __shared__ float tile[64][65];
    int b = blockIdx.z;
    int r0 = blockIdx.y * 64, s0 = blockIdx.x * 64;
    const float* pin = in + (size_t)b * R * S;
    float* pout = out + (size_t)b * R * S;
    int tr = threadIdx.x >> 4;
    int ts = (threadIdx.x & 15) << 2;
#pragma unroll
    for (int i = 0; i < 4; ++i) {
        int r = tr + i * 16;
        float4 v = *(const float4*)&pin[(size_t)(r0 + r) * S + s0 + ts];
        tile[r][ts + 0] = v.x; tile[r][ts + 1] = v.y;
        tile[r][ts + 2] = v.z; tile[r][ts + 3] = v.w;
    }
    __syncthreads();
#pragma unroll
    for (int i = 0; i < 4; ++i) {
        int s = tr + i * 16;
        float4 v = make_float4(tile[ts + 0][s], tile[ts + 1][s], tile[ts + 2][s], tile[ts + 3][s]);
        *(float4*)&pout[(size_t)(s0 + s) * R + r0 + ts] = v;
    }
}

// ---------------- KNN: wave-local, order-stat-seeded u16 bisection ----------------
// 16 rows per 1024-thr block; wave wid owns row i0+wid end-to-end (no atomics,
// one barrier for cloud staging). 64 dists/lane packed as 32 u16 pairs.
// Seeding: m21 = 21st-largest per-lane max satisfies count(d>m21)>=21, found by
// ~14 ballot iterations on ONE value/lane; the main 64-value count then hits
// window [21,128] in ~1-3 iterations (vs ~14 from [0,max] in R8).
__global__ __launch_bounds__(1024, 8) void knn_kernel(const float* __restrict__ xyz,
                                                      int* __restrict__ idx) {
    __shared__ __align__(16) float xs[N];
    __shared__ __align__(16) float ys[N];
    __shared__ __align__(16) float zs[N];
    __shared__ unsigned long long cand[16][CCAP];

    const int tid = threadIdx.x;
    const int wid = tid >> 6, lane = tid & 63;
    const int blk = blockIdx.x;                 // 0..2047
    const int b = blk >> 8;                     // 256 blocks per batch
    const int i0 = (blk & 255) << 4;            // 16 rows per block
    const float* __restrict__ xb = xyz + (size_t)b * 3 * N;

    {   // stage cloud: one float4 per plane per thread
        int p4 = tid << 2;
        *(float4*)&xs[p4] = *(const float4*)&xb[p4];
        *(float4*)&ys[p4] = *(const float4*)&xb[N + p4];
        *(float4*)&zs[p4] = *(const float4*)&xb[2 * N + p4];
    }
    const int i = i0 + wid;
    const float xix = xb[i], xiy = xb[N + i], xiz = xb[2 * N + i];
    __syncthreads();

    // distance pass: 64 dists/lane, quantize to u16 (monotone for d>=0), pack
    unsigned int dq[32];
    unsigned int mq = 0;                        // per-lane max (u16)
#pragma unroll
    for (int u = 0; u < 16; ++u) {
        int j = u * 256 + (lane << 2);
        float4 xv = *(const float4*)&xs[j];
        float4 yv = *(const float4*)&ys[j];
        float4 zv = *(const float4*)&zs[j];
        unsigned int q0 = __float_as_uint(pdist(xix, xiy, xiz, xv.x, yv.x, zv.x)) >> 16;
        unsigned int q1 = __float_as_uint(pdist(xix, xiy, xiz, xv.y, yv.y, zv.y)) >> 16;
        unsigned int q2 = __float_as_uint(pdist(xix, xiy, xiz, xv.z, yv.z, zv.z)) >> 16;
        unsigned int q3 = __float_as_uint(pdist(xix, xiy, xiz, xv.w, yv.w, zv.w)) >> 16;
        dq[2 * u]     = q0 | (q1 << 16);
        dq[2 * u + 1] = q2 | (q3 << 16);
        mq = max(mq, max(max(q0, q1), max(q2, q3)));
    }
    unsigned int m1 = mq;
#pragma unroll
    for (int off = 32; off; off >>= 1)
        m1 = max(m1, (unsigned int)__shfl_xor((int)m1, off));

    // seed: t0 with count(Lmax > t0) >= 21  (ballot on ONE value per lane)
    unsigned int slo = 0, shi = m1;
    while (shi - slo > 1u) {
        unsigned int mid = (slo + shi) >> 1;
        int c = __popcll(__ballot(mq > mid));
        if (c >= K + 1) slo = mid; else shi = mid;
    }
    const unsigned int t0 = slo;               // count(d > t0) >= 21 guaranteed (non-degenerate)

    // main: find thr with count(d > thr) in [21, CWIN]
    unsigned int thr = t0, cl = 0, tot = 0;
    bool ok = false;
    {
        unsigned int lo2 = t0, hi2 = m1;
        for (int it = 0; it < 18; ++it) {
            unsigned int t = (it == 0) ? t0 : ((lo2 + hi2) >> 1);
            unsigned int cm = (t << 16) | 0xFFFFu;
            unsigned int c = 0;
#pragma unroll
            for (int p = 0; p < 32; ++p) {
                c += ((dq[p] & 0xFFFFu) > t) ? 1u : 0u;
                c += (dq[p] > cm) ? 1u : 0u;
            }
            unsigned int ct = c;
#pragma unroll
            for (int off = 32; off; off >>= 1)
                ct += (unsigned int)__shfl_xor((int)ct, off);
            if (ct >= (unsigned)(K + 1) && ct <= (unsigned)CWIN) {
                thr = t; cl = c; tot = ct; ok = true; break;
            }
            if (ct > (unsigned)CWIN) lo2 = t; else hi2 = t;
            if (hi2 - lo2 <= 1u) { thr = lo2; break; }
        }
        if (!ok) {   // rare: recount at fallback thr
            unsigned int cm = (thr << 16) | 0xFFFFu;
            unsigned int c = 0;
#pragma unroll
            for (int p = 0; p < 32; ++p) {
                c += ((dq[p] & 0xFFFFu) > thr) ? 1u : 0u;
                c += (dq[p] > cm) ? 1u : 0u;
            }
            cl = c;
            unsigned int ct = c;
#pragma unroll
            for (int off = 32; off; off >>= 1)
                ct += (unsigned int)__shfl_xor((int)ct, off);
            tot = ct;
        }
    }

    // exclusive prefix of per-lane candidate counts
    unsigned int incl = cl;
#pragma unroll
    for (int off = 1; off < 64; off <<= 1) {
        unsigned int v = (unsigned int)__shfl_up((int)incl, off);
        if (lane >= off) incl += v;
    }
    unsigned int pos = incl - cl;

    // emit candidates (exact f32 d recomputed with identical fmaf chain)
    const unsigned int cm2 = (thr << 16) | 0xFFFFu;
#pragma unroll
    for (int p = 0; p < 32; ++p) {
        int jb = (p >> 1) * 256 + (lane << 2) + ((p & 1) << 1);
        if ((dq[p] & 0xFFFFu) > thr) {
            float d = pdist(xix, xiy, xiz, xs[jb], ys[jb], zs[jb]);
            if (pos < (unsigned)CCAP)
                cand[wid][pos] = ((unsigned long long)__float_as_uint(d) << 32)
                                 | (unsigned int)(~jb);
            ++pos;
        }
        if (dq[p] > cm2) {
            int j1 = jb + 1;
            float d = pdist(xix, xiy, xiz, xs[j1], ys[j1], zs[j1]);
            if (pos < (unsigned)CCAP)
                cand[wid][pos] = ((unsigned long long)__float_as_uint(d) << 32)
                                 | (unsigned int)(~j1);
            ++pos;
        }
    }

    // wave-local exact rank among candidates
    unsigned int cnt_r = tot < (unsigned)CCAP ? tot : (unsigned)CCAP;
    int row = (b << 12) + i;
    if (cnt_r < (unsigned)(K + 1)) {            // degenerate guard: always write idx
        if (lane < K) idx[(size_t)row * K + lane] = lane + 1;
    }
    for (unsigned int s = lane; s < cnt_r; s += 64) {
        unsigned long long my = cand[wid][s];
        int rank = 0;
        for (unsigned int t2 = 0; t2 < cnt_r; ++t2)
            rank += (cand[wid][t2] > my) ? 1 : 0;
        if (rank >= 1 && rank <= K)
            idx[(size_t)row * K + (rank - 1)] = (int)(~(unsigned int)my);
    }
}

// ---------------- gather-sum: sT[n][c] = sum_k lrelu(pt[idx[n][k]][c]) ----------------
__global__ __launch_bounds__(256) void gather_sum(const float* __restrict__ pt,
                                                  const int* __restrict__ idx,
                                                  float* __restrict__ sT) {
    int t = blockIdx.x * 256 + threadIdx.x;
    int pnt = t >> 5;
    int c4 = (t & 31) << 2;
    int b = pnt >> 12;
    const float* pb = pt + (size_t)b * N * C;
    const int* ip = idx + (size_t)pnt * K;
    float4 acc = make_float4(0.f, 0.f, 0.f, 0.f);
#pragma unroll 4
    for (int k = 0; k < K; ++k) {
        int j = ip[k] & (N - 1);    // mask: identity on valid data, crash-proof otherwise
        float4 v = *(const float4*)&pb[(size_t)j * C + c4];
        acc.x += lrelu(v.x); acc.y += lrelu(v.y);
        acc.z += lrelu(v.z); acc.w += lrelu(v.w);
    }
    *(float4*)&sT[(size_t)pnt * C + c4] = acc;
}

// ---------------- GEMM helpers ----------------
__device__ __forceinline__ void stage_ws(const float* __restrict__ Wt, float (*Ws)[128],
                                         int c0, int tid) {
#pragma unroll
    for (int q = 0; q < 2; ++q) {
        int slot = q * 256 + tid;
        int kk = slot >> 5, oo = (slot & 31) << 2;
        *(float4*)&Ws[kk][oo] = *(const float4*)&Wt[(size_t)(c0 + kk) * C + oo];
    }
}

template<bool LR>
__device__ __forceinline__ void mm_tileP(const float (*P)[132], const float (*Ws)[128],
                                         float acc[4][8], int r0, int o0, int c0) {
#pragma unroll
    for (int q = 0; q < 4; ++q) {
        float4 aj[4];
#pragma unroll
        for (int j = 0; j < 4; ++j) {
            float4 v = *(const float4*)&P[r0 + j][c0 + q * 4];
            if (LR) { v.x = lrelu(v.x); v.y = lrelu(v.y); v.z = lrelu(v.z); v.w = lrelu(v.w); }
            aj[j] = v;
        }
#pragma unroll
        for (int kq = 0; kq < 4; ++kq) {
            int kk = q * 4 + kq;
            float4 w0 = *(const float4*)&Ws[kk][o0];
            float4 w1 = *(const float4*)&Ws[kk][o0 + 64];
#pragma unroll
            for (int j = 0; j < 4; ++j) {
                float a = (kq == 0) ? aj[j].x : (kq == 1) ? aj[j].y : (kq == 2) ? aj[j].z : aj[j].w;
                acc[j][0] = fmaf(a, w0.x, acc[j][0]); acc[j][1] = fmaf(a, w0.y, acc[j][1]);
                acc[j][2] = fmaf(a, w0.z, acc[j][2]); acc[j][3] = fmaf(a, w0.w, acc[j][3]);
                acc[j][4] = fmaf(a, w1.x, acc[j][4]); acc[j][5] = fmaf(a, w1.y, acc[j][5]);
                acc[j][6] = fmaf(a, w1.z, acc[j][6]); acc[j][7] = fmaf(a, w1.w, acc[j][7]);
            }
        }
    }
}

__device__ __forceinline__ void mm_tileA(const float (*As)[20], const float (*Ws)[128],
                                         float acc[4][8], int r0, int o0) {
#pragma unroll
    for (int q = 0; q < 4; ++q) {
        float4 aj[4];
#pragma unroll
        for (int j = 0; j < 4; ++j)
            aj[j] = *(const float4*)&As[r0 + j][q * 4];
#pragma unroll
        for (int kq = 0; kq < 4; ++kq) {
            int kk = q * 4 + kq;
            float4 w0 = *(const float4*)&Ws[kk][o0];
            float4 w1 = *(const float4*)&Ws[kk][o0 + 64];
#pragma unroll
            for (int j = 0; j < 4; ++j) {
                float a = (kq == 0) ? aj[j].x : (kq == 1) ? aj[j].y : (kq == 2) ? aj[j].z : aj[j].w;
                acc[j][0] = fmaf(a, w0.x, acc[j][0]); acc[j][1] = fmaf(a, w0.y, acc[j][1]);
                acc[j][2] = fmaf(a, w0.z, acc[j][2]); acc[j][3] = fmaf(a, w0.w, acc[j][3]);
                acc[j][4] = fmaf(a, w1.x, acc[j][4]); acc[j][5] = fmaf(a, w1.y, acc[j][5]);
                acc[j][6] = fmaf(a, w1.z, acc[j][6]); acc[j][7] = fmaf(a, w1.w, acc[j][7]);
            }
        }
    }
}

// ---------------- block 0: out = lrelu(A0)@Wt0 + A1@Wt1 + bias0 + A0 ----------------
__global__ __launch_bounds__(256) void gemm_block0(const float* __restrict__ A0,
                                                   const float* __restrict__ A1,
                                                   const float* __restrict__ Wt0,
                                                   const float* __restrict__ Wt1,
                                                   const float* __restrict__ bias0,
                                                   float* __restrict__ out) {
    __shared__ float P0[64][132];
    __shared__ float As[64][20];
    __shared__ float Ws[16][128];
    const int row0 = blockIdx.x * 64;
    const int tid = threadIdx.x;
    const int r0 = (tid >> 4) << 2;
    const int o0 = (tid & 15) << 2;

#pragma unroll
    for (int q = 0; q < 8; ++q) {
        int s = q * 256 + tid;
        int r = s >> 5, c4 = (s & 31) << 2;
        *(float4*)&P0[r][c4] = *(const float4*)&A0[(size_t)(row0 + r) * C + c4];
    }

    float acc[4][8];
#pragma unroll
    for (int j = 0; j < 4; ++j)
#pragma unroll
        for (int l = 0; l < 8; ++l) acc[j][l] = 0.f;

    for (int c0 = 0; c0 < C; c0 += 16) {
        stage_ws(Wt0, Ws, c0, tid);
        __syncthreads();
        mm_tileP<true>(P0, Ws, acc, r0, o0, c0);
        __syncthreads();
    }
    for (int c0 = 0; c0 < C; c0 += 16) {
        stage_ws(Wt1, Ws, c0, tid);
        {
            int r_ld = tid >> 2, c_ld = (tid & 3) << 2;
            *(float4*)&As[r_ld][c_ld] = *(const float4*)&A1[(size_t)(row0 + r_ld) * C + c0 + c_ld];
        }
        __syncthreads();
        mm_tileA(As, Ws, acc, r0, o0);
        __syncthreads();
    }

    float4 bb0 = *(const float4*)&bias0[o0];
    float4 bb1 = *(const float4*)&bias0[o0 + 64];
#pragma unroll
    for (int j = 0; j < 4; ++j) {
        int rl = r0 + j;
        size_t r = (size_t)(row0 + rl);
        float4 s0 = *(const float4*)&P0[rl][o0];
        float4 s1 = *(const float4*)&P0[rl][o0 + 64];
        float4 v0 = make_float4(acc[j][0] + bb0.x + s0.x, acc[j][1] + bb0.y + s0.y,
                                acc[j][2] + bb0.z + s0.z, acc[j][3] + bb0.w + s0.w);
        float4 v1 = make_float4(acc[j][4] + bb1.x + s1.x, acc[j][5] + bb1.y + s1.y,
                                acc[j][6] + bb1.z + s1.z, acc[j][7] + bb1.w + s1.w);
        *(float4*)&out[r * C + o0] = v0;
        *(float4*)&out[r * C + o0 + 64] = v1;
    }
}

// ---------------- blocks 1+2 fused, epilogue writes d_out transposed [B][C][N] ------------
__global__ __launch_bounds__(256) void gemm_block12(const float* __restrict__ A0,
                                                    const float* __restrict__ Wt1,
                                                    const float* __restrict__ Wt2,
                                                    const float* __restrict__ biasAll,
                                                    float* __restrict__ outT) {
    __shared__ float P[64][132];
    __shared__ float Ws[16][128];
    const int row0 = blockIdx.x * 64;
    const int tid = threadIdx.x;
    const int r0 = (tid >> 4) << 2;
    const int o0 = (tid & 15) << 2;

#pragma unroll
    for (int q = 0; q < 8; ++q) {
        int s = q * 256 + tid;
        int r = s >> 5, c4 = (s & 31) << 2;
        *(float4*)&P[r][c4] = *(const float4*)&A0[(size_t)(row0 + r) * C + c4];
    }

    float acc[4][8];
#pragma unroll
    for (int j = 0; j < 4; ++j)
#pragma unroll
        for (int l = 0; l < 8; ++l) acc[j][l] = 0.f;

    for (int c0 = 0; c0 < C; c0 += 16) {
        stage_ws(Wt1, Ws, c0, tid);
        __syncthreads();
        mm_tileP<true>(P, Ws, acc, r0, o0, c0);
        __syncthreads();
    }
    {
        float4 bb0 = *(const float4*)&biasAll[C + o0];
        float4 bb1 = *(const float4*)&biasAll[C + o0 + 64];
#pragma unroll
        for (int j = 0; j < 4; ++j) {
            int rl = r0 + j;
            float4 s0 = *(const float4*)&P[rl][o0];
            float4 s1 = *(const float4*)&P[rl][o0 + 64];
            float4 v0 = make_float4(acc[j][0] + bb0.x + s0.x, acc[j][1] + bb0.y + s0.y,
                                    acc[j][2] + bb0.z + s0.z, acc[j][3] + bb0.w + s0.w);
            float4 v1 = make_float4(acc[j][4] + bb1.x + s1.x, acc[j][5] + bb1.y + s1.y,
                                    acc[j][6] + bb1.z + s1.z, acc[j][7] + bb1.w + s1.w);
            *(float4*)&P[rl][o0] = v0;
            *(float4*)&P[rl][o0 + 64] = v1;
            acc[j][0] = 0.f; acc[j][1] = 0.f; acc[j][2] = 0.f; acc[j][3] = 0.f;
            acc[j][4] = 0.f; acc[j][5] = 0.f; acc[j][6] = 0.f; acc[j][7] = 0.f;
        }
    }
    __syncthreads();
    for (int c0 = 0; c0 < C; c0 += 16) {
        stage_ws(Wt2, Ws, c0, tid);
        __syncthreads();
        mm_tileP<true>(P, Ws, acc, r0, o0, c0);
        __syncthreads();
    }
    {
        float4 bb0 = *(const float4*)&biasAll[2 * C + o0];
        float4 bb1 = *(const float4*)&biasAll[2 * C + o0 + 64];
#pragma unroll
        for (int j = 0; j < 4; ++j) {
            int rl = r0 + j;
            float4 s0 = *(const float4*)&P[rl][o0];
            float4 s1 = *(const float4*)&P[rl][o0 + 64];
            float4 v0 = make_float4(acc[j][0] + bb0.x + s0.x, acc[j][1] + bb0.y + s0.y,
                                    acc[j][2] + bb0.z + s0.z, acc[j][3] + bb0.w + s0.w);
            float4 v1 = make_float4(acc[j][4] + bb1.x + s1.x, acc[j][5] + bb1.y + s1.y,
                                    acc[j][6] + bb1.z + s1.z, acc[j][7] + bb1.w + s1.w);
            *(float4*)&P[rl][o0] = v0;
            *(float4*)&P[rl][o0 + 64] = v1;
        }
    }
    __syncthreads();
    const int o = tid >> 1;
    const int nh = (tid & 1) << 5;
    const int bq = row0 >> 12;
    const int nb = (row0 & (N - 1)) + nh;
    float* po = outT + ((size_t)bq * C + o) * N + nb;
#pragma unroll
    for (int q = 0; q < 8; ++q) {
        int n = nh + q * 4;
        float4 v = make_float4(P[n + 0][o], P[n + 1][o], P[n + 2][o], P[n + 3][o]);
        *(float4*)&po[q * 4] = v;
    }
}

extern "C" void kernel_launch(void* const* d_in, const int* in_sizes, int n_in,
                              void* d_out, int out_size, void* d_ws, size_t ws_size,
                              hipStream_t stream) {
    const float* xyz    = (const float*)d_in[0];
    const float* points = (const float*)d_in[1];
    const float* W1     = (const float*)d_in[2];
    const float* b1     = (const float*)d_in[3];
    const float* W2     = (const float*)d_in[4];
    const float* b2     = (const float*)d_in[5];

    float* ws = (float*)d_ws;
    float* pt_a = ws + (size_t)B * N * 4;      // [M][C]
    float* pt_b = pt_a + (size_t)M * C;
    float* sT   = pt_b + (size_t)M * C;
    float* wt   = sT + (size_t)M * C;          // 4*C*C
    float* bias = wt + 4 * C * C;              // 3*C
    int*   idx  = (int*)(bias + 3 * C);        // [M][K]

    prep_all<<<64, 256, 0, stream>>>(W1, b1, W2, b2, wt, bias);
    {
        dim3 g(N / 64, C / 64, B);
        transpose_rs<<<g, 256, 0, stream>>>(points, pt_a, C, N);   // [C][N] -> [N][C]
    }
    knn_kernel<<<M / 16, 1024, 0, stream>>>(xyz, idx);
    gather_sum<<<(M * 32) / 256, 256, 0, stream>>>(pt_a, idx, sT);
    gemm_block0<<<M / 64, 256, 0, stream>>>(pt_a, sT, wt, wt + C * C, bias, pt_b);
    gemm_block12<<<M / 64, 256, 0, stream>>>(pt_b, wt + 2 * C * C, wt + 3 * C * C, bias,
                                             (float*)d_out);
}

// Round 10
// 241.718 us; speedup vs baseline: 1.4182x; 1.4182x over previous
//
#include <hip/hip_runtime.h>
#include <math.h>

#define B 8
#define N 4096
#define C 128
#define K 20
#define M (B*N)
#define CCAP 128   // candidate buffer per wave
#define CWIN 120   // acceptance window upper bound

__device__ __forceinline__ float lrelu(float x) { return x > 0.f ? x : 0.01f * x; }

__device__ __forceinline__ float pdist(float xix, float xiy, float xiz,
                                       float xjx, float xjy, float xjz) {
    float dx = xix - xjx, dy = xiy - xjy, dz = xiz - xjz;
    return fmaf(dx, dx, fmaf(dy, dy, dz * dz));   // >= 0 always
}

// ---------------- prep: weights only ----------------
__global__ void prep_all(const float* __restrict__ W1, const float* __restrict__ b1,
                         const float* __restrict__ W2, const float* __restrict__ b2,
                         float* __restrict__ wt, float* __restrict__ bias) {
    int t = blockIdx.x * 256 + threadIdx.x;       // 0..16383
    int c = t >> 7, o = t & 127;
    int oc = o * C + c;
    wt[t]             = W1[oc] * (1.f / 21.f);
    wt[C * C + t]     = W2[oc] * (1.f / 21.f);
    wt[2 * C * C + t] = (W1[C * C + oc] + W2[C * C + oc]) * 0.5f;
    wt[3 * C * C + t] = (W1[2 * C * C + oc] + W2[2 * C * C + oc]) * 0.5f;
    if (t < C) {
        bias[t]         = (b1[t] + 20.f * b2[t]) * (1.f / 21.f);
        bias[C + t]     = (b1[C + t] + b2[C + t]) * 0.5f;
        bias[2 * C + t] = (b1[2 * C + t] + b2[2 * C + t]) * 0.5f;
    }
}

// ---------------- per-batch transpose [C][N] -> [N][C] ----------------
__global__ __launch_bounds__(256) void transpose_rs(const float* __restrict__ in,
                                                    float* __restrict__ out, int R, int S) {
    __shared__ float tile[64][65];
    int b = blockIdx.z;
    int r0 = blockIdx.y * 64, s0 = blockIdx.x * 64;
    const float* pin = in + (size_t)b * R * S;
    float* pout = out + (size_t)b * R * S;
    int tr = threadIdx.x >> 4;
    int ts = (threadIdx.x & 15) << 2;
#pragma unroll
    for (int i = 0; i < 4; ++i) {
        int r = tr + i * 16;
        float4 v = *(const float4*)&pin[(size_t)(r0 + r) * S + s0 + ts];
        tile[r][ts + 0] = v.x; tile[r][ts + 1] = v.y;
        tile[r][ts + 2] = v.z; tile[r][ts + 3] = v.w;
    }
    __syncthreads();
#pragma unroll
    for (int i = 0; i < 4; ++i) {
        int s = tr + i * 16;
        float4 v = make_float4(tile[ts + 0][s], tile[ts + 1][s], tile[ts + 2][s], tile[ts + 3][s]);
        *(float4*)&pout[(size_t)(s0 + s) * R + r0 + ts] = v;
    }
}

// ---------------- KNN: LDS-u16 distances, wave-local seeded bisection ----------------
// R9 post-mortem: any >=32-value per-thread array spills (allocator gave 32
// VGPR, 1 GB HBM scratch traffic). So distances live in LDS as quantized u16
// (monotone for d>=0; count(d16>q) == count(d32 > bitcast(q<<16|0xFFFF))).
// 256 thr = 4 waves, wave owns one row + its own LDS strip: NO barriers, NO
// atomics. Layout dq32[row][p*64+lane]: consecutive lanes -> consecutive
// banks on every write/read (conflict-free). Seed from per-lane max (21st-
// largest lane-max t0 guarantees count>=21), then 1-3 full counts.
__global__ __launch_bounds__(256) void knn_kernel(const float* __restrict__ xyz,
                                                  int* __restrict__ idx) {
    __shared__ unsigned int dq32[4][2048];        // 32 KB: u16 dists packed 2/u32
    __shared__ unsigned long long cand[4][CCAP];  // 4 KB

    const int tid = threadIdx.x;
    const int wid = tid >> 6, lane = tid & 63;
    const int blk = blockIdx.x;                 // 0..8191
    const int b = blk >> 10;
    const int i0 = (blk & 1023) << 2;
    const float* __restrict__ xb = xyz + (size_t)b * 3 * N;

    const int i = i0 + wid;
    const float xix = xb[i], xiy = xb[N + i], xiz = xb[2 * N + i];
    unsigned int* __restrict__ dl = dq32[wid];

    // distance pass: 64 pts/lane (j = u*256 + lane*4 + 0..3), quantize+pack+store
    unsigned int mq = 0;
#pragma unroll
    for (int u = 0; u < 16; ++u) {
        int j = u * 256 + (lane << 2);
        float4 xv = *(const float4*)&xb[j];
        float4 yv = *(const float4*)&xb[N + j];
        float4 zv = *(const float4*)&xb[2 * N + j];
        unsigned int q0 = __float_as_uint(pdist(xix, xiy, xiz, xv.x, yv.x, zv.x)) >> 16;
        unsigned int q1 = __float_as_uint(pdist(xix, xiy, xiz, xv.y, yv.y, zv.y)) >> 16;
        unsigned int q2 = __float_as_uint(pdist(xix, xiy, xiz, xv.z, yv.z, zv.z)) >> 16;
        unsigned int q3 = __float_as_uint(pdist(xix, xiy, xiz, xv.w, yv.w, zv.w)) >> 16;
        dl[(2 * u) * 64 + lane]     = q0 | (q1 << 16);
        dl[(2 * u + 1) * 64 + lane] = q2 | (q3 << 16);
        mq = max(mq, max(max(q0, q1), max(q2, q3)));
    }
    unsigned int m1 = mq;
#pragma unroll
    for (int off = 32; off; off >>= 1)
        m1 = max(m1, (unsigned int)__shfl_xor((int)m1, off));

    // seed: largest t0 with count(lane-max > t0) >= 21  => count(d > t0) >= 21
    unsigned int slo = 0, shi = m1;
    while (shi - slo > 1u) {
        unsigned int mid = (slo + shi) >> 1;
        int c = __popcll(__ballot(mq > mid));
        if (c >= K + 1) slo = mid; else shi = mid;
    }
    unsigned int thr = slo, cl = 0, tot = 0;

    // main: find thr with total count in [21, CWIN]; count from LDS
    {
        unsigned int lo2 = slo, hi2 = m1;
        bool ok = false;
        for (int it = 0; it < 18 && !ok; ++it) {
            unsigned int t = (it == 0) ? slo : ((lo2 + hi2) >> 1);
            unsigned int cm = (t << 16) | 0xFFFFu;
            unsigned int c = 0;
#pragma unroll
            for (int p = 0; p < 32; ++p) {
                unsigned int v = dl[p * 64 + lane];
                c += ((v & 0xFFFFu) > t) ? 1u : 0u;
                c += (v > cm) ? 1u : 0u;
            }
            unsigned int ct = c;
#pragma unroll
            for (int off = 32; off; off >>= 1)
                ct += (unsigned int)__shfl_xor((int)ct, off);
            if (ct >= (unsigned)(K + 1) && ct <= (unsigned)CWIN) {
                thr = t; cl = c; tot = ct; ok = true;
            } else {
                if (ct > (unsigned)CWIN) lo2 = t; else hi2 = t;
                if (hi2 - lo2 <= 1u) {      // exhausted: take lo2 (count >= 21)
                    thr = lo2;
                    unsigned int cm2 = (thr << 16) | 0xFFFFu;
                    unsigned int c2 = 0;
#pragma unroll
                    for (int p = 0; p < 32; ++p) {
                        unsigned int v = dl[p * 64 + lane];
                        c2 += ((v & 0xFFFFu) > thr) ? 1u : 0u;
                        c2 += (v > cm2) ? 1u : 0u;
                    }
                    cl = c2;
                    unsigned int ct2 = c2;
#pragma unroll
                    for (int off = 32; off; off >>= 1)
                        ct2 += (unsigned int)__shfl_xor((int)ct2, off);
                    tot = ct2; ok = true;
                }
            }
        }
    }

    // exclusive prefix of per-lane counts
    unsigned int incl = cl;
#pragma unroll
    for (int off = 1; off < 64; off <<= 1) {
        unsigned int v = (unsigned int)__shfl_up((int)incl, off);
        if (lane >= off) incl += v;
    }
    unsigned int pos = incl - cl;

    // emit candidates: re-scan LDS, recompute exact f32 dist (identical fmaf chain)
    const unsigned int cm2 = (thr << 16) | 0xFFFFu;
#pragma unroll
    for (int p = 0; p < 32; ++p) {
        unsigned int v = dl[p * 64 + lane];
        int jb = (p >> 1) * 256 + (lane << 2) + ((p & 1) << 1);
        if ((v & 0xFFFFu) > thr) {
            float d = pdist(xix, xiy, xiz, xb[jb], xb[N + jb], xb[2 * N + jb]);
            if (pos < (unsigned)CCAP)
                cand[wid][pos] = ((unsigned long long)__float_as_uint(d) << 32)
                                 | (unsigned int)(~jb);
            ++pos;
        }
        if (v > cm2) {
            int j1 = jb + 1;
            float d = pdist(xix, xiy, xiz, xb[j1], xb[N + j1], xb[2 * N + j1]);
            if (pos < (unsigned)CCAP)
                cand[wid][pos] = ((unsigned long long)__float_as_uint(d) << 32)
                                 | (unsigned int)(~j1);
            ++pos;
        }
    }

    // wave-local exact rank (key = d32 bits desc, then lower index)
    unsigned int cnt_r = tot < (unsigned)CCAP ? tot : (unsigned)CCAP;
    int row = (b << 12) + i;
    if (cnt_r < (unsigned)(K + 1)) {            // degenerate guard: always write idx
        if (lane < K) idx[(size_t)row * K + lane] = lane + 1;
    }
    for (unsigned int s = lane; s < cnt_r; s += 64) {
        unsigned long long my = cand[wid][s];
        int rank = 0;
        for (unsigned int t2 = 0; t2 < cnt_r; ++t2)
            rank += (cand[wid][t2] > my) ? 1 : 0;
        if (rank >= 1 && rank <= K)
            idx[(size_t)row * K + (rank - 1)] = (int)(~(unsigned int)my);
    }
}

// ---------------- gather-sum: sT[n][c] = sum_k lrelu(pt[idx[n][k]][c]) ----------------
__global__ __launch_bounds__(256) void gather_sum(const float* __restrict__ pt,
                                                  const int* __restrict__ idx,
                                                  float* __restrict__ sT) {
    int t = blockIdx.x * 256 + threadIdx.x;
    int pnt = t >> 5;
    int c4 = (t & 31) << 2;
    int b = pnt >> 12;
    const float* pb = pt + (size_t)b * N * C;
    const int* ip = idx + (size_t)pnt * K;
    float4 acc = make_float4(0.f, 0.f, 0.f, 0.f);
#pragma unroll 4
    for (int k = 0; k < K; ++k) {
        int j = ip[k] & (N - 1);    // mask: identity on valid data, crash-proof otherwise
        float4 v = *(const float4*)&pb[(size_t)j * C + c4];
        acc.x += lrelu(v.x); acc.y += lrelu(v.y);
        acc.z += lrelu(v.z); acc.w += lrelu(v.w);
    }
    *(float4*)&sT[(size_t)pnt * C + c4] = acc;
}

// ---------------- GEMM helpers ----------------
__device__ __forceinline__ void stage_ws(const float* __restrict__ Wt, float (*Ws)[128],
                                         int c0, int tid) {
#pragma unroll
    for (int q = 0; q < 2; ++q) {
        int slot = q * 256 + tid;
        int kk = slot >> 5, oo = (slot & 31) << 2;
        *(float4*)&Ws[kk][oo] = *(const float4*)&Wt[(size_t)(c0 + kk) * C + oo];
    }
}

template<bool LR>
__device__ __forceinline__ void mm_tileP(const float (*P)[132], const float (*Ws)[128],
                                         float acc[4][8], int r0, int o0, int c0) {
#pragma unroll
    for (int q = 0; q < 4; ++q) {
        float4 aj[4];
#pragma unroll
        for (int j = 0; j < 4; ++j) {
            float4 v = *(const float4*)&P[r0 + j][c0 + q * 4];
            if (LR) { v.x = lrelu(v.x); v.y = lrelu(v.y); v.z = lrelu(v.z); v.w = lrelu(v.w); }
            aj[j] = v;
        }
#pragma unroll
        for (int kq = 0; kq < 4; ++kq) {
            int kk = q * 4 + kq;
            float4 w0 = *(const float4*)&Ws[kk][o0];
            float4 w1 = *(const float4*)&Ws[kk][o0 + 64];
#pragma unroll
            for (int j = 0; j < 4; ++j) {
                float a = (kq == 0) ? aj[j].x : (kq == 1) ? aj[j].y : (kq == 2) ? aj[j].z : aj[j].w;
                acc[j][0] = fmaf(a, w0.x, acc[j][0]); acc[j][1] = fmaf(a, w0.y, acc[j][1]);
                acc[j][2] = fmaf(a, w0.z, acc[j][2]); acc[j][3] = fmaf(a, w0.w, acc[j][3]);
                acc[j][4] = fmaf(a, w1.x, acc[j][4]); acc[j][5] = fmaf(a, w1.y, acc[j][5]);
                acc[j][6] = fmaf(a, w1.z, acc[j][6]); acc[j][7] = fmaf(a, w1.w, acc[j][7]);
            }
        }
    }
}

__device__ __forceinline__ void mm_tileA(const float (*As)[20], const float (*Ws)[128],
                                         float acc[4][8], int r0, int o0) {
#pragma unroll
    for (int q = 0; q < 4; ++q) {
        float4 aj[4];
#pragma unroll
        for (int j = 0; j < 4; ++j)
            aj[j] = *(const float4*)&As[r0 + j][q * 4];
#pragma unroll
        for (int kq = 0; kq < 4; ++kq) {
            int kk = q * 4 + kq;
            float4 w0 = *(const float4*)&Ws[kk][o0];
            float4 w1 = *(const float4*)&Ws[kk][o0 + 64];
#pragma unroll
            for (int j = 0; j < 4; ++j) {
                float a = (kq == 0) ? aj[j].x : (kq == 1) ? aj[j].y : (kq == 2) ? aj[j].z : aj[j].w;
                acc[j][0] = fmaf(a, w0.x, acc[j][0]); acc[j][1] = fmaf(a, w0.y, acc[j][1]);
                acc[j][2] = fmaf(a, w0.z, acc[j][2]); acc[j][3] = fmaf(a, w0.w, acc[j][3]);
                acc[j][4] = fmaf(a, w1.x, acc[j][4]); acc[j][5] = fmaf(a, w1.y, acc[j][5]);
                acc[j][6] = fmaf(a, w1.z, acc[j][6]); acc[j][7] = fmaf(a, w1.w, acc[j][7]);
            }
        }
    }
}

// ---------------- block 0: out = lrelu(A0)@Wt0 + A1@Wt1 + bias0 + A0 ----------------
__global__ __launch_bounds__(256) void gemm_block0(const float* __restrict__ A0,
                                                   const float* __restrict__ A1,
                                                   const float* __restrict__ Wt0,
                                                   const float* __restrict__ Wt1,
                                                   const float* __restrict__ bias0,
                                                   float* __restrict__ out) {
    __shared__ float P0[64][132];
    __shared__ float As[64][20];
    __shared__ float Ws[16][128];
    const int row0 = blockIdx.x * 64;
    const int tid = threadIdx.x;
    const int r0 = (tid >> 4) << 2;
    const int o0 = (tid & 15) << 2;

#pragma unroll
    for (int q = 0; q < 8; ++q) {
        int s = q * 256 + tid;
        int r = s >> 5, c4 = (s & 31) << 2;
        *(float4*)&P0[r][c4] = *(const float4*)&A0[(size_t)(row0 + r) * C + c4];
    }

    float acc[4][8];
#pragma unroll
    for (int j = 0; j < 4; ++j)
#pragma unroll
        for (int l = 0; l < 8; ++l) acc[j][l] = 0.f;

    for (int c0 = 0; c0 < C; c0 += 16) {
        stage_ws(Wt0, Ws, c0, tid);
        __syncthreads();
        mm_tileP<true>(P0, Ws, acc, r0, o0, c0);
        __syncthreads();
    }
    for (int c0 = 0; c0 < C; c0 += 16) {
        stage_ws(Wt1, Ws, c0, tid);
        {
            int r_ld = tid >> 2, c_ld = (tid & 3) << 2;
            *(float4*)&As[r_ld][c_ld] = *(const float4*)&A1[(size_t)(row0 + r_ld) * C + c0 + c_ld];
        }
        __syncthreads();
        mm_tileA(As, Ws, acc, r0, o0);
        __syncthreads();
    }

    float4 bb0 = *(const float4*)&bias0[o0];
    float4 bb1 = *(const float4*)&bias0[o0 + 64];
#pragma unroll
    for (int j = 0; j < 4; ++j) {
        int rl = r0 + j;
        size_t r = (size_t)(row0 + rl);
        float4 s0 = *(const float4*)&P0[rl][o0];
        float4 s1 = *(const float4*)&P0[rl][o0 + 64];
        float4 v0 = make_float4(acc[j][0] + bb0.x + s0.x, acc[j][1] + bb0.y + s0.y,
                                acc[j][2] + bb0.z + s0.z, acc[j][3] + bb0.w + s0.w);
        float4 v1 = make_float4(acc[j][4] + bb1.x + s1.x, acc[j][5] + bb1.y + s1.y,
                                acc[j][6] + bb1.z + s1.z, acc[j][7] + bb1.w + s1.w);
        *(float4*)&out[r * C + o0] = v0;
        *(float4*)&out[r * C + o0 + 64] = v1;
    }
}

// ---------------- blocks 1+2 fused, epilogue writes d_out transposed [B][C][N] ------------
__global__ __launch_bounds__(256) void gemm_block12(const float* __restrict__ A0,
                                                    const float* __restrict__ Wt1,
                                                    const float* __restrict__ Wt2,
                                                    const float* __restrict__ biasAll,
                                                    float* __restrict__ outT) {
    __shared__ float P[64][132];
    __shared__ float Ws[16][128];
    const int row0 = blockIdx.x * 64;
    const int tid = threadIdx.x;
    const int r0 = (tid >> 4) << 2;
    const int o0 = (tid & 15) << 2;

#pragma unroll
    for (int q = 0; q < 8; ++q) {
        int s = q * 256 + tid;
        int r = s >> 5, c4 = (s & 31) << 2;
        *(float4*)&P[r][c4] = *(const float4*)&A0[(size_t)(row0 + r) * C + c4];
    }

    float acc[4][8];
#pragma unroll
    for (int j = 0; j < 4; ++j)
#pragma unroll
        for (int l = 0; l < 8; ++l) acc[j][l] = 0.f;

    for (int c0 = 0; c0 < C; c0 += 16) {
        stage_ws(Wt1, Ws, c0, tid);
        __syncthreads();
        mm_tileP<true>(P, Ws, acc, r0, o0, c0);
        __syncthreads();
    }
    {
        float4 bb0 = *(const float4*)&biasAll[C + o0];
        float4 bb1 = *(const float4*)&biasAll[C + o0 + 64];
#pragma unroll
        for (int j = 0; j < 4; ++j) {
            int rl = r0 + j;
            float4 s0 = *(const float4*)&P[rl][o0];
            float4 s1 = *(const float4*)&P[rl][o0 + 64];
            float4 v0 = make_float4(acc[j][0] + bb0.x + s0.x, acc[j][1] + bb0.y + s0.y,
                                    acc[j][2] + bb0.z + s0.z, acc[j][3] + bb0.w + s0.w);
            float4 v1 = make_float4(acc[j][4] + bb1.x + s1.x, acc[j][5] + bb1.y + s1.y,
                                    acc[j][6] + bb1.z + s1.z, acc[j][7] + bb1.w + s1.w);
            *(float4*)&P[rl][o0] = v0;
            *(float4*)&P[rl][o0 + 64] = v1;
            acc[j][0] = 0.f; acc[j][1] = 0.f; acc[j][2] = 0.f; acc[j][3] = 0.f;
            acc[j][4] = 0.f; acc[j][5] = 0.f; acc[j][6] = 0.f; acc[j][7] = 0.f;
        }
    }
    __syncthreads();
    for (int c0 = 0; c0 < C; c0 += 16) {
        stage_ws(Wt2, Ws, c0, tid);
        __syncthreads();
        mm_tileP<true>(P, Ws, acc, r0, o0, c0);
        __syncthreads();
    }
    {
        float4 bb0 = *(const float4*)&biasAll[2 * C + o0];
        float4 bb1 = *(const float4*)&biasAll[2 * C + o0 + 64];
#pragma unroll
        for (int j = 0; j < 4; ++j) {
            int rl = r0 + j;
            float4 s0 = *(const float4*)&P[rl][o0];
            float4 s1 = *(const float4*)&P[rl][o0 + 64];
            float4 v0 = make_float4(acc[j][0] + bb0.x + s0.x, acc[j][1] + bb0.y + s0.y,
                                    acc[j][2] + bb0.z + s0.z, acc[j][3] + bb0.w + s0.w);
            float4 v1 = make_float4(acc[j][4] + bb1.x + s1.x, acc[j][5] + bb1.y + s1.y,
                                    acc[j][6] + bb1.z + s1.z, acc[j][7] + bb1.w + s1.w);
            *(float4*)&P[rl][o0] = v0;
            *(float4*)&P[rl][o0 + 64] = v1;
        }
    }
    __syncthreads();
    const int o = tid >> 1;
    const int nh = (tid & 1) << 5;
    const int bq = row0 >> 12;
    const int nb = (row0 & (N - 1)) + nh;
    float* po = outT + ((size_t)bq * C + o) * N + nb;
#pragma unroll
    for (int q = 0; q < 8; ++q) {
        int n = nh + q * 4;
        float4 v = make_float4(P[n + 0][o], P[n + 1][o], P[n + 2][o], P[n + 3][o]);
        *(float4*)&po[q * 4] = v;
    }
}

extern "C" void kernel_launch(void* const* d_in, const int* in_sizes, int n_in,
                              void* d_out, int out_size, void* d_ws, size_t ws_size,
                              hipStream_t stream) {
    const float* xyz    = (const float*)d_in[0];
    const float* points = (const float*)d_in[1];
    const float* W1     = (const float*)d_in[2];
    const float* b1     = (const float*)d_in[3];
    const float* W2     = (const float*)d_in[4];
    const float* b2     = (const float*)d_in[5];

    float* ws = (float*)d_ws;
    float* pt_a = ws + (size_t)B * N * 4;      // [M][C]
    float* pt_b = pt_a + (size_t)M * C;
    float* sT   = pt_b + (size_t)M * C;
    float* wt   = sT + (size_t)M * C;          // 4*C*C
    float* bias = wt + 4 * C * C;              // 3*C
    int*   idx  = (int*)(bias + 3 * C);        // [M][K]

    prep_all<<<64, 256, 0, stream>>>(W1, b1, W2, b2, wt, bias);
    {
        dim3 g(N / 64, C / 64, B);
        transpose_rs<<<g, 256, 0, stream>>>(points, pt_a, C, N);   // [C][N] -> [N][C]
    }
    knn_kernel<<<M / 4, 256, 0, stream>>>(xyz, idx);
    gather_sum<<<(M * 32) / 256, 256, 0, stream>>>(pt_a, idx, sT);
    gemm_block0<<<M / 64, 256, 0, stream>>>(pt_a, sT, wt, wt + C * C, bias, pt_b);
    gemm_block12<<<M / 64, 256, 0, stream>>>(pt_b, wt + 2 * C * C, wt + 3 * C * C, bias,
                                             (float*)d_out);
}